// Round 3
// baseline (1610.680 us; speedup 1.0000x reference)
//
#include <hip/hip_runtime.h>

// BsplineEncoding: N=1M, D=3, K=64, cubic. Row = 195 fp32/point; 780 MB out.
//
// Ledger:
//  R2/R3/R5 (prev session): three structures, dur_us ~768 ("kernel ~270us,
//    2.9 TB/s" was INFERRED as dur - fill, never measured directly).
//  R6b/R7: + __builtin_nontemporal_store -> dur 766.7. NULL.
//  R8: fill-shaped phase 2 (LDS tile in output layout, 12 batched
//    ds_read_b128 -> 12 back-to-back NT store_dwordx4) -> dur 763.7. NULL.
//  Two structural nulls => the "kernel = 270us" decomposition is suspect.
//    Timed window = fill(3.12GB, ~494us, measured) + hidden tiny dispatches
//    + kernel. If hidden costs ~120us, kernel is ALREADY at ~130-150us,
//    i.e. at the 124us store roofline (780MB @ 6.3TB/s) and both nulls are
//    expected.
//  R9 (this): CALIBRATION. Extra block 0 spins s_memrealtime for 100000 RTC
//    ticks (1ms @100MHz; 4ms if RTC=25MHz - windows don't overlap, self-
//    disambiguating). Kernel duration = max(spin, work) = spin. So:
//      fixed_overhead = dur_us - spin;  true_work = 763.7 - fixed_overhead.
//    Predict: dur ~1495-1515 -> kernel ~270, attack store path (sc1) next.
//             dur ~1615-1645 -> kernel ~130-150, at roofline; stop.
//    Work blocks byte-identical to R8 (bid = blockIdx.x - 1).

typedef float vfloat4 __attribute__((ext_vector_type(4)));

constexpr int   DIMS        = 3;
constexpr int   K           = 64;
constexpr int   ROW         = DIMS * (1 + K);          // 195
constexpr float SCALE       = 30.5f;                   // (K-3)/2
constexpr float CLAMP_MAX   = 61.0f - 1e-6f;
constexpr int   PTS_PER_BLK = 64;
constexpr int   PAIRS       = PTS_PER_BLK * DIMS;      // 192 (point,dim) pairs
constexpr int   FLT_PER_BLK = PTS_PER_BLK * ROW;       // 12480
constexpr int   V4_PER_BLK  = FLT_PER_BLK / 4;         // 3120
constexpr int   FULL_ITERS  = V4_PER_BLK / 256;        // 12
constexpr int   TAIL        = V4_PER_BLK - FULL_ITERS * 256;  // 48

__global__ __launch_bounds__(256)
void bspline_kernel(const float* __restrict__ x, float* __restrict__ out,
                    int n_pairs_total) {
    // ---- Calibration spinner: block 0 burns a known wall-time ----
    if (blockIdx.x == 0) {
        if (threadIdx.x == 0) {
            const unsigned long long t0 = __builtin_amdgcn_s_memrealtime();
            while (__builtin_amdgcn_s_memrealtime() - t0 < 100000ULL) {}
        }
        return;
    }
    const int bid = blockIdx.x - 1;                    // work-block index

    // Final output tile, exactly in output layout: pair p -> floats
    // [p*65 .. p*65+64] = [xv, feat[0..63]].
    __shared__ __align__(16) float tile[FLT_PER_BLK];  // 49.92 KB -> 3 blk/CU
    vfloat4* t4 = reinterpret_cast<vfloat4*>(tile);
    const int t = threadIdx.x;

    // ---- Phase 0: zero the tile (conflict-free b128 writes) ----
    const vfloat4 z = {0.0f, 0.0f, 0.0f, 0.0f};
#pragma unroll
    for (int i = 0; i < FULL_ITERS; ++i) t4[t + i * 256] = z;
    if (t < TAIL) t4[FULL_ITERS * 256 + t] = z;
    __syncthreads();

    // ---- Phase 1: one param eval per (point,dim); scatter 5 floats ----
    if (t < PAIRS) {
        const int gp = bid * PAIRS + t;                // global pair = n*3+d
        float xv = 0.0f;
        if (gp < n_pairs_total) xv = x[gp];            // coalesced
        float xs = (xv + 1.0f) * SCALE;
        xs = fminf(fmaxf(xs, 0.0f), CLAMP_MAX);
        const int   idx = (int)xs;                     // xs>=0: trunc==floor
        const float u   = xs - (float)idx;
        const float u2  = u * u;
        const float u3  = u2 * u;
        const float om  = 1.0f - u;
        float* base = tile + t * 65;
        base[0]       = xv;
        base[1 + idx] = om * om * om * (1.0f / 6.0f);
        base[2 + idx] = (3.0f * u3 - 6.0f * u2 + 4.0f) * (1.0f / 6.0f);
        base[3 + idx] = (-3.0f * u3 + 3.0f * u2 + 3.0f * u + 1.0f) * (1.0f / 6.0f);
        base[4 + idx] = u3 * (1.0f / 6.0f);
    }
    __syncthreads();

    // ---- Phase 2: fill-shaped stream. 12 batched ds_read_b128 into regs,
    // then 12 back-to-back NT store_dwordx4 (no per-store LDS dependency) ----
    vfloat4* out4 = reinterpret_cast<vfloat4*>(out)
                  + (long long)bid * V4_PER_BLK;
    vfloat4 v[FULL_ITERS];
#pragma unroll
    for (int i = 0; i < FULL_ITERS; ++i) v[i] = t4[t + i * 256];
#pragma unroll
    for (int i = 0; i < FULL_ITERS; ++i)
        __builtin_nontemporal_store(v[i], &out4[t + i * 256]);
    if (t < TAIL) {
        const vfloat4 vt = t4[FULL_ITERS * 256 + t];
        __builtin_nontemporal_store(vt, &out4[FULL_ITERS * 256 + t]);
    }
}

extern "C" void kernel_launch(void* const* d_in, const int* in_sizes, int n_in,
                              void* d_out, int out_size, void* d_ws, size_t ws_size,
                              hipStream_t stream) {
    const float* x  = (const float*)d_in[0];
    float* out      = (float*)d_out;
    const int n_pts = in_sizes[0] / DIMS;                         // 1,000,000
    const int nblk  = (n_pts + PTS_PER_BLK - 1) / PTS_PER_BLK;    // 15625
    // +1: block 0 is the calibration spinner; work blocks use bid-1.
    bspline_kernel<<<dim3(nblk + 1), dim3(256), 0, stream>>>(x, out, n_pts * DIMS);
}

// Round 4
// 761.729 us; speedup vs baseline: 2.1145x; 2.1145x over previous
//
#include <hip/hip_runtime.h>

// BsplineEncoding: N=1M, D=3, K=64, cubic. Row = 195 fp32/point; 780 MB out.
//
// Ledger:
//  R2-R8: three structures + NT stores + fill-shaped phase2 all ~764 us
//    harness dur. R9 CALIBRATION (1ms spinner block, RTC=100MHz) resolved:
//    true kernel work = 1002 - (1610.7-763.7) = ~155 us; fixed harness
//    overhead ~609 us (fill 494 + ~115 hidden). Prev session's "270 us
//    kernel" was wrong; R6b/R8 nulls explained (already near floor).
//    Counters from pinned dispatch: WRITE_SIZE 762.5 MB (exact), FETCH
//    5.9 MB (input only) => NT stores DO bypass write-allocate.
//  Floor: (780 MB wr + 12 MB rd) @ 6.3 TB/s = 126 us. W=155 => 5.1 TB/s,
//    80% of achievable. Addressable headroom ~30 us (~4% of dur_us).
//  R10 (this): spinner removed; PTS_PER_BLK 64->32 => LDS 25 KB => 6 blk/CU
//    (24 waves/CU, was 3 blk/12 waves; LDS was the occupancy binder, VGPR=68
//    fine). Doubles store-stream overlap to hide per-block overhead
//    (zero+2 barriers+phase1 across 2x more resident blocks).
//    Predict: dur 763.7 -> ~735-745 (kernel 155 -> ~130). If null: residual
//    is launch/drain-irreducible => declare roofline.

typedef float vfloat4 __attribute__((ext_vector_type(4)));

constexpr int   DIMS        = 3;
constexpr int   K           = 64;
constexpr int   ROW         = DIMS * (1 + K);          // 195
constexpr float SCALE       = 30.5f;                   // (K-3)/2
constexpr float CLAMP_MAX   = 61.0f - 1e-6f;
constexpr int   PTS_PER_BLK = 32;
constexpr int   PAIRS       = PTS_PER_BLK * DIMS;      // 96 (point,dim) pairs
constexpr int   FLT_PER_BLK = PTS_PER_BLK * ROW;       // 6240
constexpr int   V4_PER_BLK  = FLT_PER_BLK / 4;         // 1560
constexpr int   FULL_ITERS  = V4_PER_BLK / 256;        // 6
constexpr int   TAIL        = V4_PER_BLK - FULL_ITERS * 256;  // 24

__global__ __launch_bounds__(256)
void bspline_kernel(const float* __restrict__ x, float* __restrict__ out,
                    int n_pairs_total) {
    // Final output tile, exactly in output layout: pair p -> floats
    // [p*65 .. p*65+64] = [xv, feat[0..63]].
    __shared__ __align__(16) float tile[FLT_PER_BLK];  // 24.96 KB -> 6 blk/CU
    vfloat4* t4 = reinterpret_cast<vfloat4*>(tile);
    const int t = threadIdx.x;

    // ---- Phase 0: zero the tile (conflict-free b128 writes) ----
    const vfloat4 z = {0.0f, 0.0f, 0.0f, 0.0f};
#pragma unroll
    for (int i = 0; i < FULL_ITERS; ++i) t4[t + i * 256] = z;
    if (t < TAIL) t4[FULL_ITERS * 256 + t] = z;
    __syncthreads();

    // ---- Phase 1: one param eval per (point,dim); scatter 5 floats ----
    if (t < PAIRS) {
        const int gp = blockIdx.x * PAIRS + t;         // global pair = n*3+d
        float xv = 0.0f;
        if (gp < n_pairs_total) xv = x[gp];            // coalesced
        float xs = (xv + 1.0f) * SCALE;
        xs = fminf(fmaxf(xs, 0.0f), CLAMP_MAX);
        const int   idx = (int)xs;                     // xs>=0: trunc==floor
        const float u   = xs - (float)idx;
        const float u2  = u * u;
        const float u3  = u2 * u;
        const float om  = 1.0f - u;
        float* base = tile + t * 65;
        base[0]       = xv;
        base[1 + idx] = om * om * om * (1.0f / 6.0f);
        base[2 + idx] = (3.0f * u3 - 6.0f * u2 + 4.0f) * (1.0f / 6.0f);
        base[3 + idx] = (-3.0f * u3 + 3.0f * u2 + 3.0f * u + 1.0f) * (1.0f / 6.0f);
        base[4 + idx] = u3 * (1.0f / 6.0f);
    }
    __syncthreads();

    // ---- Phase 2: fill-shaped stream. 6 batched ds_read_b128 into regs,
    // then 6 back-to-back NT store_dwordx4 (no per-store LDS dependency) ----
    vfloat4* out4 = reinterpret_cast<vfloat4*>(out)
                  + (long long)blockIdx.x * V4_PER_BLK;
    vfloat4 v[FULL_ITERS];
#pragma unroll
    for (int i = 0; i < FULL_ITERS; ++i) v[i] = t4[t + i * 256];
#pragma unroll
    for (int i = 0; i < FULL_ITERS; ++i)
        __builtin_nontemporal_store(v[i], &out4[t + i * 256]);
    if (t < TAIL) {
        const vfloat4 vt = t4[FULL_ITERS * 256 + t];
        __builtin_nontemporal_store(vt, &out4[FULL_ITERS * 256 + t]);
    }
}

extern "C" void kernel_launch(void* const* d_in, const int* in_sizes, int n_in,
                              void* d_out, int out_size, void* d_ws, size_t ws_size,
                              hipStream_t stream) {
    const float* x  = (const float*)d_in[0];
    float* out      = (float*)d_out;
    const int n_pts = in_sizes[0] / DIMS;                         // 1,000,000
    const int nblk  = (n_pts + PTS_PER_BLK - 1) / PTS_PER_BLK;    // 31250
    bspline_kernel<<<dim3(nblk), dim3(256), 0, stream>>>(x, out, n_pts * DIMS);
}